// Round 3
// baseline (123.086 us; speedup 1.0000x reference)
//
#include <hip/hip_runtime.h>
#include <math.h>

#define SEQ   2048
#define NH    8
#define DH    64          // p
#define DS    16          // n
#define NBH   512         // BATCH * NH
#define OUTBH 1024        // DH * DS

// One block per (segment, b, h). 256 threads = 4 waves.
// Each lane accumulates a 4p x 4n register tile; waves split the segment's
// timesteps (interleaved by 4); cross-wave reduce in LDS at the end.
__global__ __launch_bounds__(256, 4)
void ssd_state_partial(const float* __restrict__ Xg,
                       const float* __restrict__ Ag,
                       const float* __restrict__ Bg,
                       float* __restrict__ dst,
                       int seglen)
{
    extern __shared__ float sm[];
    float* wseg    = sm;            // seglen floats: per-t weights for this segment
    float* scratch = sm + seglen;   // 4096 floats: scan buffer, then reduce buffer

    const int tid = threadIdx.x;
    const int bid = blockIdx.x;
    const int bh  = bid & (NBH - 1);
    const int g   = bid >> 9;       // log2(NBH) = 9
    const int b   = bh >> 3;
    const int h   = bh & 7;
    const int t0  = g * seglen;

    // ---------------- phase 1: w[t] = exp(sum_{s>t} A[b,s,h]) ----------------
    // Full-row suffix scan (every block recomputes its (b,h) row; A is tiny/L2-hot).
    const float* Ab = Ag + (size_t)b * SEQ * NH + h;
    float a[8];
#pragma unroll
    for (int k = 0; k < 8; ++k)
        a[k] = Ab[(size_t)(tid * 8 + k) * NH];
    float tot = 0.f;
#pragma unroll
    for (int k = 0; k < 8; ++k) tot += a[k];
    scratch[tid] = tot;
    __syncthreads();
    // inclusive suffix scan over the 256 per-thread totals (Hillis-Steele)
    for (int off = 1; off < 256; off <<= 1) {
        float v = scratch[tid];
        float u = (tid + off < 256) ? scratch[tid + off] : 0.f;
        __syncthreads();
        scratch[tid] = v + u;
        __syncthreads();
    }
    float run = (tid < 255) ? scratch[tid + 1] : 0.f;  // sum over s >= (tid+1)*8
#pragma unroll
    for (int k = 7; k >= 0; --k) {
        int t = tid * 8 + k;
        // run == sum_{s > t} A[s]
        if (t >= t0 && t < t0 + seglen)
            wseg[t - t0] = expf(run);
        run += a[k];
    }
    __syncthreads();

    // ---------------- phase 2: streaming weighted outer-product ----------------
    const int wave = tid >> 6;
    const int lane = tid & 63;
    const int p0 = (lane & 15) << 2;   // 4 consecutive p
    const int n0 = (lane >> 4) << 2;   // 4 consecutive n

    const float* Xp = Xg + (((size_t)b * SEQ + t0) * NH + h) * DH + p0;
    const float* Bp = Bg + (((size_t)b * SEQ + t0) * NH + h) * DS + n0;

    float acc[4][4];
#pragma unroll
    for (int i = 0; i < 4; ++i)
#pragma unroll
        for (int j = 0; j < 4; ++j) acc[i][j] = 0.f;

#pragma unroll 4
    for (int tt = wave; tt < seglen; tt += 4) {
        float4 xv = *(const float4*)(Xp + (size_t)tt * (NH * DH));
        float4 bv = *(const float4*)(Bp + (size_t)tt * (NH * DS));
        float wt  = wseg[tt];                         // wave-uniform broadcast
        float xs0 = xv.x * wt, xs1 = xv.y * wt, xs2 = xv.z * wt, xs3 = xv.w * wt;
        acc[0][0] = fmaf(xs0, bv.x, acc[0][0]);
        acc[0][1] = fmaf(xs0, bv.y, acc[0][1]);
        acc[0][2] = fmaf(xs0, bv.z, acc[0][2]);
        acc[0][3] = fmaf(xs0, bv.w, acc[0][3]);
        acc[1][0] = fmaf(xs1, bv.x, acc[1][0]);
        acc[1][1] = fmaf(xs1, bv.y, acc[1][1]);
        acc[1][2] = fmaf(xs1, bv.z, acc[1][2]);
        acc[1][3] = fmaf(xs1, bv.w, acc[1][3]);
        acc[2][0] = fmaf(xs2, bv.x, acc[2][0]);
        acc[2][1] = fmaf(xs2, bv.y, acc[2][1]);
        acc[2][2] = fmaf(xs2, bv.z, acc[2][2]);
        acc[2][3] = fmaf(xs2, bv.w, acc[2][3]);
        acc[3][0] = fmaf(xs3, bv.x, acc[3][0]);
        acc[3][1] = fmaf(xs3, bv.y, acc[3][1]);
        acc[3][2] = fmaf(xs3, bv.z, acc[3][2]);
        acc[3][3] = fmaf(xs3, bv.w, acc[3][3]);
    }

    // ---------------- phase 3: cross-wave reduce + store ----------------
    float* red = scratch;   // 4 waves x 1024 floats
#pragma unroll
    for (int i = 0; i < 4; ++i) {
        float4 v = make_float4(acc[i][0], acc[i][1], acc[i][2], acc[i][3]);
        *(float4*)&red[wave * OUTBH + (p0 + i) * DS + n0] = v;
    }
    __syncthreads();
    {
        int o = tid * 4;
        float4 r0 = *(const float4*)&red[o];
        float4 r1 = *(const float4*)&red[OUTBH + o];
        float4 r2 = *(const float4*)&red[2 * OUTBH + o];
        float4 r3 = *(const float4*)&red[3 * OUTBH + o];
        float4 s = make_float4(r0.x + r1.x + r2.x + r3.x,
                               r0.y + r1.y + r2.y + r3.y,
                               r0.z + r1.z + r2.z + r3.z,
                               r0.w + r1.w + r2.w + r3.w);
        *(float4*)(dst + (size_t)bid * OUTBH + o) = s;
    }
}

// Sum the NSEG=4 segment partials into the final output.
__global__ __launch_bounds__(256)
void seg_reduce4(const float* __restrict__ part, float* __restrict__ out)
{
    int i = blockIdx.x * 256 + threadIdx.x;
    size_t o = (size_t)i * 4;
    float4 s = make_float4(0.f, 0.f, 0.f, 0.f);
#pragma unroll
    for (int g2 = 0; g2 < 4; ++g2) {
        float4 v = *(const float4*)(part + (size_t)g2 * NBH * OUTBH + o);
        s.x += v.x; s.y += v.y; s.z += v.z; s.w += v.w;
    }
    *(float4*)(out + o) = s;
}

extern "C" void kernel_launch(void* const* d_in, const int* in_sizes, int n_in,
                              void* d_out, int out_size, void* d_ws, size_t ws_size,
                              hipStream_t stream)
{
    const float* X  = (const float*)d_in[0];
    const float* A  = (const float*)d_in[1];
    const float* Bm = (const float*)d_in[2];
    // d_in[3] (C) is unused by the reference output.
    float* out = (float*)d_out;

    const size_t need = (size_t)4 * NBH * OUTBH * sizeof(float);  // 8 MB
    const int nseg   = (d_ws && ws_size >= need) ? 4 : 1;
    const int seglen = SEQ / nseg;
    float* dst = (nseg == 4) ? (float*)d_ws : out;
    const size_t lds = (size_t)(seglen + 4096) * sizeof(float);

    ssd_state_partial<<<dim3(nseg * NBH), dim3(256), lds, stream>>>(X, A, Bm, dst, seglen);
    if (nseg == 4)
        seg_reduce4<<<dim3((NBH * OUTBH) / 1024), dim3(256), 0, stream>>>((const float*)d_ws, out);
}